// Round 1
// 162.982 us; speedup vs baseline: 1.0811x; 1.0811x over previous
//
#include <hip/hip_runtime.h>
#include <hip/hip_bf16.h>

// ---------------------------------------------------------------------------
// PointNet Feature Propagation, MI355X (gfx950)
//   K1a: chunked 3-NN scan, packed-key (d|idx) min/max network, SGPR k-data
//   K1b: merge 24 keys -> quantized top-6 -> exact-d rescue top-3 -> interp
//   K2:  MFMA GEMM1 128x256 full-N, BK=64, dbuf global_load_lds, XOR-swizzle
//   K3:  finalize BN0
//   K4:  MFMA GEMM2 128x128 full-N, BN0+ReLU fused in reg-staged A
//   K5:  finalize BN1
//   K6:  BN1+ReLU -> out f32
// BN is shift-invariant => conv biases b0/b1 cancel exactly; skipped.
// ---------------------------------------------------------------------------

typedef __attribute__((ext_vector_type(8))) short short8;
typedef __attribute__((ext_vector_type(4))) float f32x4;

#define BB 8
#define NN 8192
#define SS 2048
#define M_TOT (BB * NN)      // 65536 points
#define K1DIM 384
#define N1DIM 256
#define K2DIM 256
#define N2DIM 128
#define NCH 8
#define CHS (SS / NCH)
#define BK 64                // K-step (128 bytes/row in LDS tiles)

// key = (d_bits & KEY_MASK) | global_idx  (11 idx bits; d>=0 so u32 order = f32 order)
#define KEY_MASK 0xFFFFF800u
#define IDX_MASK 0x7FFu

__device__ __forceinline__ unsigned short f2bf(float f) {
    unsigned int x = __float_as_uint(f);
    unsigned int r = x + 0x7fffu + ((x >> 16) & 1u);  // RNE
    return (unsigned short)(r >> 16);
}
__device__ __forceinline__ float bf2f(unsigned short u) {
    return __uint_as_float(((unsigned int)u) << 16);
}

// async 16B global->LDS (direct-to-LDS DMA; LDS dest is wave-uniform base +
// lane*16 — our per-lane expression evaluates to exactly base + lane*16)
__device__ __forceinline__ void gload_lds16(const void* g, void* lds) {
    __builtin_amdgcn_global_load_lds(
        (const __attribute__((address_space(1))) unsigned int*)g,
        (__attribute__((address_space(3))) unsigned int*)lds, 16, 0, 0);
}

// ---------------------------------------------------------------------------
// K1a: chunked 3-NN scan. Grid = 2048 blocks (8 blocks/CU).
// Per candidate: 3 sub + 3 fma + 2 pack + 5 min/max = 13 VALU, k-data via
// wave-uniform float4 load (scalar pipe). Output: 3 packed keys per chunk.
// ---------------------------------------------------------------------------
__global__ __launch_bounds__(256) void nn_cand_kernel(
    const float* __restrict__ uxyz,
    const float4* __restrict__ kpack,   // [B][S] (x,y,z,--)
    unsigned int* __restrict__ cand)    // [NCH][3][M_TOT]
{
    const int tid  = threadIdx.x;
    const int bid  = blockIdx.x;
    const int ch   = bid & 7;
    const int tile = (bid >> 3) & 31;
    const int b    = bid >> 8;

    const int n = tile * 256 + tid;
    const float* up = uxyz + ((size_t)b * NN + n) * 3;
    const float ux = up[0], uy = up[1], uz = up[2];

    const float4* kb = kpack + (size_t)b * SS + ch * CHS;
    const int base = ch * CHS;

    unsigned int k0 = 0xFFFFFFFFu, k1 = 0xFFFFFFFFu, k2 = 0xFFFFFFFFu;
#pragma unroll 8
    for (int s = 0; s < CHS; ++s) {
        float4 kc = kb[s];                       // uniform addr -> s_load_dwordx4
        float dx = kc.x - ux, dy = kc.y - uy, dz = kc.z - uz;
        float d = fmaf(dx, dx, fmaf(dy, dy, dz * dz));
        unsigned int key = (__float_as_uint(d) & KEY_MASK) | (unsigned int)(base + s);
        // 5-op top-3 insert network
        unsigned int a0 = min(key, k0);
        unsigned int m  = max(key, k0);
        k0 = a0;
        unsigned int a1 = min(m, k1);
        m = max(m, k1);
        k1 = a1;
        k2 = min(m, k2);
    }

    const size_t pt = (size_t)b * NN + n;
    cand[(size_t)(ch * 3 + 0) * M_TOT + pt] = k0;
    cand[(size_t)(ch * 3 + 1) * M_TOT + pt] = k1;
    cand[(size_t)(ch * 3 + 2) * M_TOT + pt] = k2;
}

// ---------------------------------------------------------------------------
// K1b: merge 24 keys/point -> quantized top-6 -> exact-distance rescue top-3
//      -> weights; gather features; write x bf16.
// ---------------------------------------------------------------------------
__global__ __launch_bounds__(256) void merge_interp_kernel(
    const unsigned int* __restrict__ cand,   // [NCH][3][M_TOT]
    const float4* __restrict__ kpack,        // [B][S]
    const float* __restrict__ uxyz,
    const float* __restrict__ upts,
    const float* __restrict__ kpts,
    unsigned short* __restrict__ x)
{
    __shared__ int   sidx[64][3];
    __shared__ float sw[64][3];

    const int tid = threadIdx.x;
    const int bid = blockIdx.x;
    const int b   = bid & 7;
    const int pn  = (bid >> 3) * 64;

    if (tid < 64) {
        const size_t pt = (size_t)b * NN + pn + tid;

        // merge 24 packed keys into quantized top-6 (11-op insert network)
        unsigned int k[6];
#pragma unroll
        for (int i = 0; i < 6; ++i) k[i] = 0xFFFFFFFFu;
#pragma unroll
        for (int ch = 0; ch < NCH; ++ch) {
#pragma unroll
            for (int j = 0; j < 3; ++j) {
                unsigned int t = cand[(size_t)(ch * 3 + j) * M_TOT + pt];
#pragma unroll
                for (int i = 0; i < 6; ++i) {
                    unsigned int a = min(k[i], t);
                    t = max(k[i], t);
                    k[i] = a;
                }
            }
        }

        // exact-distance rescue: recompute d for the 6 candidates, pick exact
        // top-3 with index tie-break (matches reference top_k stability)
        const float* up = uxyz + pt * 3;
        const float ux = up[0], uy = up[1], uz = up[2];
        const float4* kpb4 = kpack + (size_t)b * SS;
        unsigned long long e[6];
#pragma unroll
        for (int i = 0; i < 6; ++i) {
            unsigned int idx = k[i] & IDX_MASK;
            float4 kc = kpb4[idx];
            float dx = kc.x - ux, dy = kc.y - uy, dz = kc.z - uz;
            float d = fmaf(dx, dx, fmaf(dy, dy, dz * dz));
            e[i] = ((unsigned long long)__float_as_uint(d) << 32) | idx;
        }
#pragma unroll
        for (int i = 0; i < 3; ++i)
#pragma unroll
            for (int j = i + 1; j < 6; ++j)
                if (e[j] < e[i]) { unsigned long long t = e[i]; e[i] = e[j]; e[j] = t; }

        float d0 = __uint_as_float((unsigned int)(e[0] >> 32));
        float d1 = __uint_as_float((unsigned int)(e[1] >> 32));
        float d2 = __uint_as_float((unsigned int)(e[2] >> 32));
        float r0 = 1.0f / (d0 + 1e-8f);
        float r1 = 1.0f / (d1 + 1e-8f);
        float r2 = 1.0f / (d2 + 1e-8f);
        float rs = 1.0f / (r0 + r1 + r2);
        sidx[tid][0] = (int)(e[0] & IDX_MASK);
        sidx[tid][1] = (int)(e[1] & IDX_MASK);
        sidx[tid][2] = (int)(e[2] & IDX_MASK);
        sw[tid][0] = r0 * rs; sw[tid][1] = r1 * rs; sw[tid][2] = r2 * rs;
    }
    __syncthreads();

    const int wv = tid >> 6, lane = tid & 63;
    const float* kpb = kpts + (size_t)b * SS * N1DIM;
    const float* upb = upts + (size_t)b * NN * 128;
    for (int p = wv; p < 64; p += 4) {
        const int j0 = sidx[p][0], j1 = sidx[p][1], j2 = sidx[p][2];
        const float w0 = sw[p][0], w1 = sw[p][1], w2 = sw[p][2];
        unsigned short* xr = x + ((size_t)b * NN + pn + p) * K1DIM;

        float4 f0 = *(const float4*)(kpb + (size_t)j0 * 256 + lane * 4);
        float4 f1 = *(const float4*)(kpb + (size_t)j1 * 256 + lane * 4);
        float4 f2 = *(const float4*)(kpb + (size_t)j2 * 256 + lane * 4);
        ushort4 o;
        o.x = f2bf(w0 * f0.x + w1 * f1.x + w2 * f2.x);
        o.y = f2bf(w0 * f0.y + w1 * f1.y + w2 * f2.y);
        o.z = f2bf(w0 * f0.z + w1 * f1.z + w2 * f2.z);
        o.w = f2bf(w0 * f0.w + w1 * f1.w + w2 * f2.w);
        *(ushort4*)(xr + 128 + lane * 4) = o;

        if (lane < 32) {
            float4 u = *(const float4*)(upb + ((size_t)(pn + p)) * 128 + lane * 4);
            ushort4 q;
            q.x = f2bf(u.x); q.y = f2bf(u.y); q.z = f2bf(u.z); q.w = f2bf(u.w);
            *(ushort4*)(xr + lane * 4) = q;
        }
    }
}

// ---------------------------------------------------------------------------
// K0: convert W0, W1 to bf16; pack known xyz into float4
// ---------------------------------------------------------------------------
__global__ __launch_bounds__(256) void cvt_w_kernel(
    const float* __restrict__ W0, const float* __restrict__ W1,
    const float* __restrict__ kxyz,
    unsigned short* __restrict__ Wb0, unsigned short* __restrict__ Wb1,
    float4* __restrict__ kpack)
{
    int i = blockIdx.x * 256 + threadIdx.x;
    if (i < N1DIM * K1DIM) Wb0[i] = f2bf(W0[i]);
    if (i < N2DIM * K2DIM) Wb1[i] = f2bf(W1[i]);
    if (i < BB * SS) {
        const float* p = kxyz + (size_t)i * 3;
        kpack[i] = make_float4(p[0], p[1], p[2], 0.0f);
    }
}

// ---------------------------------------------------------------------------
// K2: GEMM1  y0 = x @ W0^T   (128x256 tile, BK=64, 8 waves 2x4)
// Double-buffered global_load_lds(16B); LDS rows 128B, XOR-swizzled via
// pre-swizzled global source (byte ^= (row&7)<<4); conflict-free b128 reads.
// ---------------------------------------------------------------------------
#define G1_NT (K1DIM / BK)   // 6
__global__ __launch_bounds__(512, 2) void gemm1_kernel(
    const unsigned short* __restrict__ X,    // [M][384]
    const unsigned short* __restrict__ Wb,   // [256][384]
    unsigned short* __restrict__ Y,          // [M][256]
    float* __restrict__ stats)               // [512]: sum|sumsq
{
    // buffer: [A 128x128B = 16K][B 256x128B = 32K], x2 = 96KB
    __shared__ __align__(128) unsigned char smem[2 * 49152];

    const int tid = threadIdx.x;
    const int l = tid & 63, w = tid >> 6;    // 8 waves
    const int wm = w >> 2, wn = w & 3;       // 2 x 4 wave grid
    const int row0 = blockIdx.x * 128;
    const int srow = l >> 3;                 // staging: 8 rows per 1KB call
    const int sbo  = (l & 7) * 16;

    f32x4 acc[4][4];
#pragma unroll
    for (int m = 0; m < 4; ++m)
#pragma unroll
        for (int n = 0; n < 4; ++n) {
            f32x4 z = {0.f, 0.f, 0.f, 0.f};
            acc[m][n] = z;
        }

    const unsigned char* Xb = (const unsigned char*)X;
    const unsigned char* Bb = (const unsigned char*)Wb;

    auto stage = [&](int buf, int t) {
        unsigned char* Al = smem + buf * 49152;
        unsigned char* Bl = Al + 16384;
        const int k0b = t * (BK * 2);
#pragma unroll
        for (int i = 0; i < 2; ++i) {        // A: 128 rows
            const int r = w * 16 + i * 8 + srow;
            gload_lds16(Xb + (size_t)(row0 + r) * (K1DIM * 2) + k0b + (sbo ^ ((r & 7) << 4)),
                        Al + r * 128 + sbo);
        }
#pragma unroll
        for (int i = 0; i < 4; ++i) {        // B: 256 rows
            const int r = w * 32 + i * 8 + srow;
            gload_lds16(Bb + (size_t)r * (K1DIM * 2) + k0b + (sbo ^ ((r & 7) << 4)),
                        Bl + r * 128 + sbo);
        }
    };

    auto compute = [&](int buf) {
        const unsigned char* Al = smem + buf * 49152;
        const unsigned char* Bl = Al + 16384;
#pragma unroll
        for (int ks = 0; ks < 2; ++ks) {
            const int bo = ks * 64 + (l >> 4) * 16;
            short8 a[4], bq[4];
#pragma unroll
            for (int m = 0; m < 4; ++m) {
                const int r = wm * 64 + m * 16 + (l & 15);
                a[m] = *(const short8*)(Al + r * 128 + (bo ^ ((r & 7) << 4)));
            }
#pragma unroll
            for (int n = 0; n < 4; ++n) {
                const int r = wn * 64 + n * 16 + (l & 15);
                bq[n] = *(const short8*)(Bl + r * 128 + (bo ^ ((r & 7) << 4)));
            }
#pragma unroll
            for (int m = 0; m < 4; ++m)
#pragma unroll
                for (int n = 0; n < 4; ++n)
                    acc[m][n] = __builtin_amdgcn_mfma_f32_16x16x32_bf16(
                        a[m], bq[n], acc[m][n], 0, 0, 0);
        }
    };

    stage(0, 0);
    __syncthreads();                          // drains vmcnt + barrier
#pragma unroll
    for (int t = 0; t < G1_NT; ++t) {
        const int cur = t & 1;
        if (t + 1 < G1_NT) stage(cur ^ 1, t + 1);  // prefetch next tile
        compute(cur);
        __syncthreads();                      // drain prefetch + sync readers
    }

    // epilogue: write Y bf16 + per-channel stats
    float s1[4] = {0.f, 0.f, 0.f, 0.f}, s2[4] = {0.f, 0.f, 0.f, 0.f};
#pragma unroll
    for (int m = 0; m < 4; ++m) {
        const int row = row0 + wm * 64 + m * 16 + (l >> 4) * 4;
#pragma unroll
        for (int n = 0; n < 4; ++n) {
            const int col = wn * 64 + n * 16 + (l & 15);
            f32x4 v = acc[m][n];
#pragma unroll
            for (int r = 0; r < 4; ++r) {
                float f = v[r];
                Y[(size_t)(row + r) * N1DIM + col] = f2bf(f);
                s1[n] += f;
                s2[n] += f * f;
            }
        }
    }
#pragma unroll
    for (int n = 0; n < 4; ++n) {
        s1[n] += __shfl_xor(s1[n], 16, 64);
        s1[n] += __shfl_xor(s1[n], 32, 64);
        s2[n] += __shfl_xor(s2[n], 16, 64);
        s2[n] += __shfl_xor(s2[n], 32, 64);
    }
    if (l < 16) {
#pragma unroll
        for (int n = 0; n < 4; ++n) {
            const int col = wn * 64 + n * 16 + l;
            atomicAdd(&stats[col], s1[n]);
            atomicAdd(&stats[N1DIM + col], s2[n]);
        }
    }
}

// ---------------------------------------------------------------------------
// K4: GEMM2  y1 = relu(bn0(y0)) @ W1^T   (128x128 tile, BK=64, 8 waves 2x4)
// A reg-staged (T14 issue-early/write-late) with BN0+ReLU fused; B via
// global_load_lds. Same XOR swizzle.
// ---------------------------------------------------------------------------
#define G2_NT (K2DIM / BK)   // 4
__global__ __launch_bounds__(512, 4) void gemm2_kernel(
    const unsigned short* __restrict__ Y0,   // [M][256] bf16
    const unsigned short* __restrict__ Wb,   // [128][256] bf16
    const float* __restrict__ gm,            // [256]
    const float* __restrict__ ga,            // [256]
    float* __restrict__ Y1,                  // [M][128] f32
    float* __restrict__ stats)               // [256]: sum|sumsq
{
    // buffer: [A 128x128B = 16K][B 128x128B = 16K], x2 = 64KB
    __shared__ __align__(128) unsigned char smem[2 * 32768];
    __shared__ float sgm[K2DIM], sga[K2DIM];

    const int tid = threadIdx.x;
    const int l = tid & 63, w = tid >> 6;
    const int wm = w >> 2, wn = w & 3;
    const int row0 = blockIdx.x * 128;
    const int srow = l >> 3;
    const int sbo  = (l & 7) * 16;
    const int lr  = tid >> 2;                // A staging row 0..127
    const int lcq = tid & 3;                 // A staging col quarter (16 elems)

    f32x4 acc[4][2];
#pragma unroll
    for (int m = 0; m < 4; ++m)
#pragma unroll
        for (int n = 0; n < 2; ++n) {
            f32x4 z = {0.f, 0.f, 0.f, 0.f};
            acc[m][n] = z;
        }

    const unsigned char* Bb = (const unsigned char*)Wb;
    short8 areg0, areg1;

    auto issueA = [&](int t) {               // global loads, used late (T14)
        const unsigned short* src = Y0 + (size_t)(row0 + lr) * K2DIM + t * BK + lcq * 16;
        areg0 = *(const short8*)src;
        areg1 = *(const short8*)(src + 8);
    };
    auto stageB = [&](int buf, int t) {
        unsigned char* Bl = smem + buf * 32768 + 16384;
        const int k0b = t * (BK * 2);
#pragma unroll
        for (int i = 0; i < 2; ++i) {        // B: 128 rows
            const int r = w * 16 + i * 8 + srow;
            gload_lds16(Bb + (size_t)r * (K2DIM * 2) + k0b + (sbo ^ ((r & 7) << 4)),
                        Bl + r * 128 + sbo);
        }
    };
    auto xformA = [&](int buf, int t) {      // BN0 + ReLU -> swizzled ds_write
        unsigned char* Al = smem + buf * 32768;
        const int kb = t * BK + lcq * 16;
        short8 o0, o1;
#pragma unroll
        for (int j = 0; j < 8; ++j) {
            float f = bf2f((unsigned short)areg0[j]);
            f = fmaxf(fmaf(f, sgm[kb + j], sga[kb + j]), 0.f);
            o0[j] = (short)f2bf(f);
            float g = bf2f((unsigned short)areg1[j]);
            g = fmaxf(fmaf(g, sgm[kb + 8 + j], sga[kb + 8 + j]), 0.f);
            o1[j] = (short)f2bf(g);
        }
        const int bo = lcq * 32;
        *(short8*)(Al + lr * 128 + ((bo) ^ ((lr & 7) << 4))) = o0;
        *(short8*)(Al + lr * 128 + ((bo + 16) ^ ((lr & 7) << 4))) = o1;
    };
    auto compute = [&](int buf) {
        const unsigned char* Al = smem + buf * 32768;
        const unsigned char* Bl = Al + 16384;
#pragma unroll
        for (int ks = 0; ks < 2; ++ks) {
            const int bo = ks * 64 + (l >> 4) * 16;
            short8 a[4], bq[2];
#pragma unroll
            for (int m = 0; m < 4; ++m) {
                const int r = wm * 64 + m * 16 + (l & 15);
                a[m] = *(const short8*)(Al + r * 128 + (bo ^ ((r & 7) << 4)));
            }
#pragma unroll
            for (int n = 0; n < 2; ++n) {
                const int r = wn * 32 + n * 16 + (l & 15);
                bq[n] = *(const short8*)(Bl + r * 128 + (bo ^ ((r & 7) << 4)));
            }
#pragma unroll
            for (int m = 0; m < 4; ++m)
#pragma unroll
                for (int n = 0; n < 2; ++n)
                    acc[m][n] = __builtin_amdgcn_mfma_f32_16x16x32_bf16(
                        a[m], bq[n], acc[m][n], 0, 0, 0);
        }
    };

    // prologue
    if (tid < K2DIM) { sgm[tid] = gm[tid]; sga[tid] = ga[tid]; }
    issueA(0);
    stageB(0, 0);
    __syncthreads();                          // sgm/sga visible, B0 done
    xformA(0, 0);
    __syncthreads();                          // A0 writes visible

#pragma unroll
    for (int t = 0; t < G2_NT; ++t) {
        const int cur = t & 1;
        if (t + 1 < G2_NT) { issueA(t + 1); stageB(cur ^ 1, t + 1); }
        compute(cur);
        if (t + 1 < G2_NT) xformA(cur ^ 1, t + 1);  // buf^1 readers done at t-1
        __syncthreads();
    }

    // epilogue
    float s1[2] = {0.f, 0.f}, s2[2] = {0.f, 0.f};
#pragma unroll
    for (int m = 0; m < 4; ++m) {
        const int row = row0 + wm * 64 + m * 16 + (l >> 4) * 4;
#pragma unroll
        for (int n = 0; n < 2; ++n) {
            const int col = wn * 32 + n * 16 + (l & 15);
            f32x4 v = acc[m][n];
#pragma unroll
            for (int r = 0; r < 4; ++r) {
                float f = v[r];
                Y1[(size_t)(row + r) * N2DIM + col] = f;
                s1[n] += f;
                s2[n] += f * f;
            }
        }
    }
#pragma unroll
    for (int n = 0; n < 2; ++n) {
        s1[n] += __shfl_xor(s1[n], 16, 64);
        s1[n] += __shfl_xor(s1[n], 32, 64);
        s2[n] += __shfl_xor(s2[n], 16, 64);
        s2[n] += __shfl_xor(s2[n], 32, 64);
    }
    if (l < 16) {
#pragma unroll
        for (int n = 0; n < 2; ++n) {
            const int col = wn * 32 + n * 16 + l;
            atomicAdd(&stats[col], s1[n]);
            atomicAdd(&stats[N2DIM + col], s2[n]);
        }
    }
}

// ---------------------------------------------------------------------------
// K3/K5: stats -> per-channel scale/bias
// ---------------------------------------------------------------------------
__global__ void finalize_stats_kernel(
    const float* __restrict__ stats, const float* __restrict__ g,
    const float* __restrict__ beta, float* __restrict__ gm,
    float* __restrict__ ga, int C)
{
    int c = blockIdx.x * blockDim.x + threadIdx.x;
    if (c < C) {
        const float inv = 1.0f / (float)M_TOT;
        float mean = stats[c] * inv;
        float var = stats[C + c] * inv - mean * mean;
        float m = g[c] * rsqrtf(var + 1e-5f);
        gm[c] = m;
        ga[c] = beta[c] - mean * m;
    }
}

// ---------------------------------------------------------------------------
// K6: out = relu(bn1(y1))
// ---------------------------------------------------------------------------
__global__ __launch_bounds__(256) void bn_out_kernel(
    const float* __restrict__ Y1, const float* __restrict__ gm,
    const float* __restrict__ ga, float* __restrict__ out)
{
    const int total = M_TOT * N2DIM / 4;
    for (int i = blockIdx.x * 256 + threadIdx.x; i < total; i += gridDim.x * 256) {
        float4 v = ((const float4*)Y1)[i];
        const int cg = (i & 31) * 4;
        float4 m = *(const float4*)(gm + cg);
        float4 a = *(const float4*)(ga + cg);
        float4 o;
        o.x = fmaxf(fmaf(v.x, m.x, a.x), 0.f);
        o.y = fmaxf(fmaf(v.y, m.y, a.y), 0.f);
        o.z = fmaxf(fmaf(v.z, m.z, a.z), 0.f);
        o.w = fmaxf(fmaf(v.w, m.w, a.w), 0.f);
        ((float4*)out)[i] = o;
    }
}

// ---------------------------------------------------------------------------
// launch
// ---------------------------------------------------------------------------
extern "C" void kernel_launch(void* const* d_in, const int* in_sizes, int n_in,
                              void* d_out, int out_size, void* d_ws, size_t ws_size,
                              hipStream_t stream)
{
    const float* uxyz  = (const float*)d_in[0];
    const float* kxyz  = (const float*)d_in[1];
    const float* upts  = (const float*)d_in[2];
    const float* kpts  = (const float*)d_in[3];
    const float* W0    = (const float*)d_in[4];
    const float* g0    = (const float*)d_in[6];
    const float* beta0 = (const float*)d_in[7];
    const float* W1    = (const float*)d_in[8];
    const float* g1    = (const float*)d_in[10];
    const float* beta1 = (const float*)d_in[11];
    float* out = (float*)d_out;

    char* ws = (char*)d_ws;
    const size_t off_x   = 0;                       // x bf16 [M][384]; y1 f32 aliased later
    const size_t off_y0  = 50331648;                // y0 bf16 [M][256]; cand+kpack aliased earlier
    const size_t off_w0  = off_y0 + 33554432;
    const size_t off_w1  = off_w0 + 196608;
    const size_t off_f   = off_w1 + 65536;

    unsigned short* x    = (unsigned short*)(ws + off_x);
    float*          y1   = (float*)(ws + off_x);
    unsigned short* y0   = (unsigned short*)(ws + off_y0);
    unsigned int*   cand = (unsigned int*)(ws + off_y0);          // 6.3 MB
    float4*         kpack = (float4*)(ws + off_y0 + 8388608);     // 256 KB
    unsigned short* wb0  = (unsigned short*)(ws + off_w0);
    unsigned short* wb1  = (unsigned short*)(ws + off_w1);
    float* F = (float*)(ws + off_f);
    float* stats0 = F;           // [512]
    float* stats1 = F + 512;     // [256]
    float* gm0 = F + 768;
    float* ga0 = F + 1024;
    float* gm1 = F + 1280;
    float* ga1 = F + 1408;

    hipMemsetAsync(stats0, 0, 768 * sizeof(float), stream);

    cvt_w_kernel<<<384, 256, 0, stream>>>(W0, W1, kxyz, wb0, wb1, kpack);
    nn_cand_kernel<<<2048, 256, 0, stream>>>(uxyz, kpack, cand);
    merge_interp_kernel<<<1024, 256, 0, stream>>>(cand, kpack, uxyz, upts, kpts, x);
    gemm1_kernel<<<M_TOT / 128, 512, 0, stream>>>(x, wb0, y0, stats0);
    finalize_stats_kernel<<<1, 256, 0, stream>>>(stats0, g0, beta0, gm0, ga0, N1DIM);
    gemm2_kernel<<<M_TOT / 128, 512, 0, stream>>>(y0, wb1, gm0, ga0, y1, stats1);
    finalize_stats_kernel<<<1, 256, 0, stream>>>(stats1, g1, beta1, gm1, ga1, N2DIM);
    bn_out_kernel<<<2048, 256, 0, stream>>>(y1, gm1, ga1, out);
}

// Round 3
// 155.858 us; speedup vs baseline: 1.1305x; 1.0457x over previous
//
#include <hip/hip_runtime.h>
#include <hip/hip_bf16.h>

// ---------------------------------------------------------------------------
// PointNet Feature Propagation, MI355X (gfx950)
//   K1a: chunked 3-NN scan, dot-form distance + med3 top-3, SGPR k-data
//   K1b: merge 24 keys -> quantized top-6 -> exact-d rescue top-3 -> interp
//   K2:  MFMA GEMM1 128x256 full-N, BK=64, dbuf global_load_lds, XOR-swizzle
//   K4:  MFMA GEMM2 128x128, BN0-finalize inline in prologue, BN0+ReLU fused A
//   K6:  bn_out: BN1-finalize inline + BN1+ReLU -> out f32
// BN is shift-invariant => conv biases b0/b1 cancel exactly; skipped.
// ---------------------------------------------------------------------------

typedef __attribute__((ext_vector_type(8))) short short8;
typedef __attribute__((ext_vector_type(4))) float f32x4;

#define BB 8
#define NN 8192
#define SS 2048
#define M_TOT (BB * NN)      // 65536 points
#define K1DIM 384
#define N1DIM 256
#define K2DIM 256
#define N2DIM 128
#define NCH 8
#define CHS (SS / NCH)
#define BK 64                // K-step (128 bytes/row in LDS tiles)

// key = (d_bits & KEY_MASK) | global_idx  (11 idx bits; d>=0 so u32 order = f32 order)
#define KEY_MASK 0xFFFFF800u
#define IDX_MASK 0x7FFu

__device__ __forceinline__ unsigned short f2bf(float f) {
    unsigned int x = __float_as_uint(f);
    unsigned int r = x + 0x7fffu + ((x >> 16) & 1u);  // RNE
    return (unsigned short)(r >> 16);
}
__device__ __forceinline__ float bf2f(unsigned short u) {
    return __uint_as_float(((unsigned int)u) << 16);
}
__device__ __forceinline__ unsigned int med3_u32(unsigned int a, unsigned int b,
                                                 unsigned int c) {
    unsigned int r;
    asm("v_med3_u32 %0, %1, %2, %3" : "=v"(r) : "v"(a), "v"(b), "v"(c));
    return r;
}

// async 16B global->LDS (direct-to-LDS DMA; LDS dest is wave-uniform base +
// lane*16 — our per-lane expression evaluates to exactly base + lane*16)
__device__ __forceinline__ void gload_lds16(const void* g, void* lds) {
    __builtin_amdgcn_global_load_lds(
        (const __attribute__((address_space(1))) unsigned int*)g,
        (__attribute__((address_space(3))) unsigned int*)lds, 16, 0, 0);
}

// ---------------------------------------------------------------------------
// K1a: chunked 3-NN scan. Grid = 2048 blocks (8 blocks/CU).
// Per candidate: 1 add + 3 fma + clamp + 2 pack + min + 2 med3 = 10 VALU.
// k-data via wave-uniform float4 load (scalar pipe); kc.w = |k|^2.
// d = (|k|^2 + |u|^2) - 2 u.k  (clamped at 0; rescue recomputes exact).
// ---------------------------------------------------------------------------
__global__ __launch_bounds__(256) void nn_cand_kernel(
    const float* __restrict__ uxyz,
    const float4* __restrict__ kpack,   // [B][S] (x,y,z,|k|^2)
    unsigned int* __restrict__ cand)    // [NCH][3][M_TOT]
{
    const int tid  = threadIdx.x;
    const int bid  = blockIdx.x;
    const int ch   = bid & 7;
    const int tile = (bid >> 3) & 31;
    const int b    = bid >> 8;

    const int n = tile * 256 + tid;
    const float* up = uxyz + ((size_t)b * NN + n) * 3;
    const float ux = up[0], uy = up[1], uz = up[2];
    const float uu  = fmaf(ux, ux, fmaf(uy, uy, uz * uz));
    const float m2x = -2.0f * ux, m2y = -2.0f * uy, m2z = -2.0f * uz;

    const float4* kb = kpack + (size_t)b * SS + ch * CHS;
    const int base = ch * CHS;

    unsigned int k0 = 0xFFFFFFFFu, k1 = 0xFFFFFFFFu, k2 = 0xFFFFFFFFu;
#pragma unroll 8
    for (int s = 0; s < CHS; ++s) {
        float4 kc = kb[s];                       // uniform addr -> s_load
        float d = kc.w + uu;                     // |k|^2 + |u|^2
        d = fmaf(m2z, kc.z, d);
        d = fmaf(m2y, kc.y, d);
        d = fmaf(m2x, kc.x, d);
        d = fmaxf(d, 0.0f);                      // cancellation guard
        unsigned int key = (__float_as_uint(d) & KEY_MASK) | (unsigned int)(base + s);
        unsigned int nk1 = med3_u32(k0, k1, key);
        unsigned int nk2 = med3_u32(k1, k2, key);
        k0 = min(k0, key);
        k1 = nk1;
        k2 = nk2;
    }

    const size_t pt = (size_t)b * NN + n;
    cand[(size_t)(ch * 3 + 0) * M_TOT + pt] = k0;
    cand[(size_t)(ch * 3 + 1) * M_TOT + pt] = k1;
    cand[(size_t)(ch * 3 + 2) * M_TOT + pt] = k2;
}

// ---------------------------------------------------------------------------
// K1b: merge 24 keys/point -> quantized top-6 -> exact-distance rescue top-3
//      -> weights; gather features; write x bf16.
// ---------------------------------------------------------------------------
__global__ __launch_bounds__(256) void merge_interp_kernel(
    const unsigned int* __restrict__ cand,   // [NCH][3][M_TOT]
    const float4* __restrict__ kpack,        // [B][S]
    const float* __restrict__ uxyz,
    const float* __restrict__ upts,
    const float* __restrict__ kpts,
    unsigned short* __restrict__ x)
{
    __shared__ int   sidx[64][3];
    __shared__ float sw[64][3];

    const int tid = threadIdx.x;
    const int bid = blockIdx.x;
    const int b   = bid & 7;
    const int pn  = (bid >> 3) * 64;

    if (tid < 64) {
        const size_t pt = (size_t)b * NN + pn + tid;

        // merge 24 packed keys into quantized top-6
        unsigned int k[6];
#pragma unroll
        for (int i = 0; i < 6; ++i) k[i] = 0xFFFFFFFFu;
#pragma unroll
        for (int ch = 0; ch < NCH; ++ch) {
#pragma unroll
            for (int j = 0; j < 3; ++j) {
                unsigned int t = cand[(size_t)(ch * 3 + j) * M_TOT + pt];
#pragma unroll
                for (int i = 0; i < 6; ++i) {
                    unsigned int a = min(k[i], t);
                    t = max(k[i], t);
                    k[i] = a;
                }
            }
        }

        // exact-distance rescue: recompute d for the 6 candidates, pick exact
        // top-3 with index tie-break (matches reference top_k stability)
        const float* up = uxyz + pt * 3;
        const float ux = up[0], uy = up[1], uz = up[2];
        const float4* kpb4 = kpack + (size_t)b * SS;
        unsigned long long e[6];
#pragma unroll
        for (int i = 0; i < 6; ++i) {
            unsigned int idx = k[i] & IDX_MASK;
            float4 kc = kpb4[idx];
            float dx = kc.x - ux, dy = kc.y - uy, dz = kc.z - uz;
            float d = fmaf(dx, dx, fmaf(dy, dy, dz * dz));
            e[i] = ((unsigned long long)__float_as_uint(d) << 32) | idx;
        }
#pragma unroll
        for (int i = 0; i < 3; ++i)
#pragma unroll
            for (int j = i + 1; j < 6; ++j)
                if (e[j] < e[i]) { unsigned long long t = e[i]; e[i] = e[j]; e[j] = t; }

        float d0 = __uint_as_float((unsigned int)(e[0] >> 32));
        float d1 = __uint_as_float((unsigned int)(e[1] >> 32));
        float d2 = __uint_as_float((unsigned int)(e[2] >> 32));
        float r0 = 1.0f / (d0 + 1e-8f);
        float r1 = 1.0f / (d1 + 1e-8f);
        float r2 = 1.0f / (d2 + 1e-8f);
        float rs = 1.0f / (r0 + r1 + r2);
        sidx[tid][0] = (int)(e[0] & IDX_MASK);
        sidx[tid][1] = (int)(e[1] & IDX_MASK);
        sidx[tid][2] = (int)(e[2] & IDX_MASK);
        sw[tid][0] = r0 * rs; sw[tid][1] = r1 * rs; sw[tid][2] = r2 * rs;
    }
    __syncthreads();

    const int wv = tid >> 6, lane = tid & 63;
    const float* kpb = kpts + (size_t)b * SS * N1DIM;
    const float* upb = upts + (size_t)b * NN * 128;
    for (int p = wv; p < 64; p += 4) {
        const int j0 = sidx[p][0], j1 = sidx[p][1], j2 = sidx[p][2];
        const float w0 = sw[p][0], w1 = sw[p][1], w2 = sw[p][2];
        unsigned short* xr = x + ((size_t)b * NN + pn + p) * K1DIM;

        float4 f0 = *(const float4*)(kpb + (size_t)j0 * 256 + lane * 4);
        float4 f1 = *(const float4*)(kpb + (size_t)j1 * 256 + lane * 4);
        float4 f2 = *(const float4*)(kpb + (size_t)j2 * 256 + lane * 4);
        ushort4 o;
        o.x = f2bf(w0 * f0.x + w1 * f1.x + w2 * f2.x);
        o.y = f2bf(w0 * f0.y + w1 * f1.y + w2 * f2.y);
        o.z = f2bf(w0 * f0.z + w1 * f1.z + w2 * f2.z);
        o.w = f2bf(w0 * f0.w + w1 * f1.w + w2 * f2.w);
        *(ushort4*)(xr + 128 + lane * 4) = o;

        if (lane < 32) {
            float4 u = *(const float4*)(upb + ((size_t)(pn + p)) * 128 + lane * 4);
            ushort4 q;
            q.x = f2bf(u.x); q.y = f2bf(u.y); q.z = f2bf(u.z); q.w = f2bf(u.w);
            *(ushort4*)(xr + lane * 4) = q;
        }
    }
}

// ---------------------------------------------------------------------------
// K0: convert W0, W1 to bf16; pack known xyz into float4 with |k|^2 in .w
// ---------------------------------------------------------------------------
__global__ __launch_bounds__(256) void cvt_w_kernel(
    const float* __restrict__ W0, const float* __restrict__ W1,
    const float* __restrict__ kxyz,
    unsigned short* __restrict__ Wb0, unsigned short* __restrict__ Wb1,
    float4* __restrict__ kpack)
{
    int i = blockIdx.x * 256 + threadIdx.x;
    if (i < N1DIM * K1DIM) Wb0[i] = f2bf(W0[i]);
    if (i < N2DIM * K2DIM) Wb1[i] = f2bf(W1[i]);
    if (i < BB * SS) {
        const float* p = kxyz + (size_t)i * 3;
        float px = p[0], py = p[1], pz = p[2];
        kpack[i] = make_float4(px, py, pz, fmaf(px, px, fmaf(py, py, pz * pz)));
    }
}

// ---------------------------------------------------------------------------
// K2: GEMM1  y0 = x @ W0^T   (128x256 tile, BK=64, 8 waves 2x4)
// Double-buffered global_load_lds(16B); LDS rows 128B, XOR-swizzled via
// pre-swizzled global source (byte ^= (row&7)<<4); conflict-free b128 reads.
// ---------------------------------------------------------------------------
#define G1_NT (K1DIM / BK)   // 6
__global__ __launch_bounds__(512, 2) void gemm1_kernel(
    const unsigned short* __restrict__ X,    // [M][384]
    const unsigned short* __restrict__ Wb,   // [256][384]
    unsigned short* __restrict__ Y,          // [M][256]
    float* __restrict__ stats)               // [512]: sum|sumsq
{
    // buffer: [A 128x128B = 16K][B 256x128B = 32K], x2 = 96KB
    __shared__ __align__(128) unsigned char smem[2 * 49152];

    const int tid = threadIdx.x;
    const int l = tid & 63, w = tid >> 6;    // 8 waves
    const int wm = w >> 2, wn = w & 3;       // 2 x 4 wave grid
    const int row0 = blockIdx.x * 128;
    const int srow = l >> 3;                 // staging: 8 rows per 1KB call
    const int sbo  = (l & 7) * 16;

    f32x4 acc[4][4];
#pragma unroll
    for (int m = 0; m < 4; ++m)
#pragma unroll
        for (int n = 0; n < 4; ++n) {
            f32x4 z = {0.f, 0.f, 0.f, 0.f};
            acc[m][n] = z;
        }

    const unsigned char* Xb = (const unsigned char*)X;
    const unsigned char* Bb = (const unsigned char*)Wb;

    auto stage = [&](int buf, int t) {
        unsigned char* Al = smem + buf * 49152;
        unsigned char* Bl = Al + 16384;
        const int k0b = t * (BK * 2);
#pragma unroll
        for (int i = 0; i < 2; ++i) {        // A: 128 rows
            const int r = w * 16 + i * 8 + srow;
            gload_lds16(Xb + (size_t)(row0 + r) * (K1DIM * 2) + k0b + (sbo ^ ((r & 7) << 4)),
                        Al + r * 128 + sbo);
        }
#pragma unroll
        for (int i = 0; i < 4; ++i) {        // B: 256 rows
            const int r = w * 32 + i * 8 + srow;
            gload_lds16(Bb + (size_t)r * (K1DIM * 2) + k0b + (sbo ^ ((r & 7) << 4)),
                        Bl + r * 128 + sbo);
        }
    };

    auto compute = [&](int buf) {
        const unsigned char* Al = smem + buf * 49152;
        const unsigned char* Bl = Al + 16384;
#pragma unroll
        for (int ks = 0; ks < 2; ++ks) {
            const int bo = ks * 64 + (l >> 4) * 16;
            short8 a[4], bq[4];
#pragma unroll
            for (int m = 0; m < 4; ++m) {
                const int r = wm * 64 + m * 16 + (l & 15);
                a[m] = *(const short8*)(Al + r * 128 + (bo ^ ((r & 7) << 4)));
            }
#pragma unroll
            for (int n = 0; n < 4; ++n) {
                const int r = wn * 64 + n * 16 + (l & 15);
                bq[n] = *(const short8*)(Bl + r * 128 + (bo ^ ((r & 7) << 4)));
            }
#pragma unroll
            for (int m = 0; m < 4; ++m)
#pragma unroll
                for (int n = 0; n < 4; ++n)
                    acc[m][n] = __builtin_amdgcn_mfma_f32_16x16x32_bf16(
                        a[m], bq[n], acc[m][n], 0, 0, 0);
        }
    };

    stage(0, 0);
    __syncthreads();                          // drains vmcnt + barrier
#pragma unroll
    for (int t = 0; t < G1_NT; ++t) {
        const int cur = t & 1;
        if (t + 1 < G1_NT) stage(cur ^ 1, t + 1);  // prefetch next tile
        compute(cur);
        __syncthreads();                      // drain prefetch + sync readers
    }

    // epilogue: write Y bf16 + per-channel stats
    float s1[4] = {0.f, 0.f, 0.f, 0.f}, s2[4] = {0.f, 0.f, 0.f, 0.f};
#pragma unroll
    for (int m = 0; m < 4; ++m) {
        const int row = row0 + wm * 64 + m * 16 + (l >> 4) * 4;
#pragma unroll
        for (int n = 0; n < 4; ++n) {
            const int col = wn * 64 + n * 16 + (l & 15);
            f32x4 v = acc[m][n];
#pragma unroll
            for (int r = 0; r < 4; ++r) {
                float f = v[r];
                Y[(size_t)(row + r) * N1DIM + col] = f2bf(f);
                s1[n] += f;
                s2[n] += f * f;
            }
        }
    }
#pragma unroll
    for (int n = 0; n < 4; ++n) {
        s1[n] += __shfl_xor(s1[n], 16, 64);
        s1[n] += __shfl_xor(s1[n], 32, 64);
        s2[n] += __shfl_xor(s2[n], 16, 64);
        s2[n] += __shfl_xor(s2[n], 32, 64);
    }
    if (l < 16) {
#pragma unroll
        for (int n = 0; n < 4; ++n) {
            const int col = wn * 64 + n * 16 + l;
            atomicAdd(&stats[col], s1[n]);
            atomicAdd(&stats[N1DIM + col], s2[n]);
        }
    }
}

// ---------------------------------------------------------------------------
// K4: GEMM2  y1 = relu(bn0(y0)) @ W1^T   (128x128 tile, BK=64, 8 waves 2x4)
// BN0 finalize inlined in the prologue (stats0 complete by stream order).
// A reg-staged (T14) with BN0+ReLU fused; B via global_load_lds.
// ---------------------------------------------------------------------------
#define G2_NT (K2DIM / BK)   // 4
__global__ __launch_bounds__(512, 4) void gemm2_kernel(
    const unsigned short* __restrict__ Y0,   // [M][256] bf16
    const unsigned short* __restrict__ Wb,   // [128][256] bf16
    const float* __restrict__ stats0,        // [512]: sum|sumsq
    const float* __restrict__ g0,            // [256]
    const float* __restrict__ beta0,         // [256]
    float* __restrict__ Y1,                  // [M][128] f32
    float* __restrict__ stats)               // [256]: sum|sumsq
{
    // buffer: [A 128x128B = 16K][B 128x128B = 16K], x2 = 64KB
    __shared__ __align__(128) unsigned char smem[2 * 32768];
    __shared__ float sgm[K2DIM], sga[K2DIM];

    const int tid = threadIdx.x;
    const int l = tid & 63, w = tid >> 6;
    const int wm = w >> 2, wn = w & 3;
    const int row0 = blockIdx.x * 128;
    const int srow = l >> 3;
    const int sbo  = (l & 7) * 16;
    const int lr  = tid >> 2;                // A staging row 0..127
    const int lcq = tid & 3;                 // A staging col quarter (16 elems)

    f32x4 acc[4][2];
#pragma unroll
    for (int m = 0; m < 4; ++m)
#pragma unroll
        for (int n = 0; n < 2; ++n) {
            f32x4 z = {0.f, 0.f, 0.f, 0.f};
            acc[m][n] = z;
        }

    const unsigned char* Bb = (const unsigned char*)Wb;
    short8 areg0, areg1;

    auto issueA = [&](int t) {               // global loads, used late (T14)
        const unsigned short* src = Y0 + (size_t)(row0 + lr) * K2DIM + t * BK + lcq * 16;
        areg0 = *(const short8*)src;
        areg1 = *(const short8*)(src + 8);
    };
    auto stageB = [&](int buf, int t) {
        unsigned char* Bl = smem + buf * 32768 + 16384;
        const int k0b = t * (BK * 2);
#pragma unroll
        for (int i = 0; i < 2; ++i) {        // B: 128 rows
            const int r = w * 16 + i * 8 + srow;
            gload_lds16(Bb + (size_t)r * (K2DIM * 2) + k0b + (sbo ^ ((r & 7) << 4)),
                        Bl + r * 128 + sbo);
        }
    };
    auto xformA = [&](int buf, int t) {      // BN0 + ReLU -> swizzled ds_write
        unsigned char* Al = smem + buf * 32768;
        const int kb = t * BK + lcq * 16;
        short8 o0, o1;
#pragma unroll
        for (int j = 0; j < 8; ++j) {
            float f = bf2f((unsigned short)areg0[j]);
            f = fmaxf(fmaf(f, sgm[kb + j], sga[kb + j]), 0.f);
            o0[j] = (short)f2bf(f);
            float g = bf2f((unsigned short)areg1[j]);
            g = fmaxf(fmaf(g, sgm[kb + 8 + j], sga[kb + 8 + j]), 0.f);
            o1[j] = (short)f2bf(g);
        }
        const int bo = lcq * 32;
        *(short8*)(Al + lr * 128 + ((bo) ^ ((lr & 7) << 4))) = o0;
        *(short8*)(Al + lr * 128 + ((bo + 16) ^ ((lr & 7) << 4))) = o1;
    };
    auto compute = [&](int buf) {
        const unsigned char* Al = smem + buf * 32768;
        const unsigned char* Bl = Al + 16384;
#pragma unroll
        for (int ks = 0; ks < 2; ++ks) {
            const int bo = ks * 64 + (l >> 4) * 16;
            short8 a[4], bq[2];
#pragma unroll
            for (int m = 0; m < 4; ++m) {
                const int r = wm * 64 + m * 16 + (l & 15);
                a[m] = *(const short8*)(Al + r * 128 + (bo ^ ((r & 7) << 4)));
            }
#pragma unroll
            for (int n = 0; n < 2; ++n) {
                const int r = wn * 32 + n * 16 + (l & 15);
                bq[n] = *(const short8*)(Bl + r * 128 + (bo ^ ((r & 7) << 4)));
            }
#pragma unroll
            for (int m = 0; m < 4; ++m)
#pragma unroll
                for (int n = 0; n < 2; ++n)
                    acc[m][n] = __builtin_amdgcn_mfma_f32_16x16x32_bf16(
                        a[m], bq[n], acc[m][n], 0, 0, 0);
        }
    };

    // prologue: BN0 finalize inline (redundant per block; 256 ch, trivial)
    if (tid < K2DIM) {
        const float inv = 1.0f / (float)M_TOT;
        float mean = stats0[tid] * inv;
        float var  = stats0[N1DIM + tid] * inv - mean * mean;
        float m = g0[tid] * rsqrtf(var + 1e-5f);
        sgm[tid] = m;
        sga[tid] = beta0[tid] - mean * m;
    }
    issueA(0);
    stageB(0, 0);
    __syncthreads();                          // sgm/sga visible, B0 done
    xformA(0, 0);
    __syncthreads();                          // A0 writes visible

#pragma unroll
    for (int t = 0; t < G2_NT; ++t) {
        const int cur = t & 1;
        if (t + 1 < G2_NT) { issueA(t + 1); stageB(cur ^ 1, t + 1); }
        compute(cur);
        if (t + 1 < G2_NT) xformA(cur ^ 1, t + 1);  // buf^1 readers done at t-1
        __syncthreads();
    }

    // epilogue
    float s1[2] = {0.f, 0.f}, s2[2] = {0.f, 0.f};
#pragma unroll
    for (int m = 0; m < 4; ++m) {
        const int row = row0 + wm * 64 + m * 16 + (l >> 4) * 4;
#pragma unroll
        for (int n = 0; n < 2; ++n) {
            const int col = wn * 32 + n * 16 + (l & 15);
            f32x4 v = acc[m][n];
#pragma unroll
            for (int r = 0; r < 4; ++r) {
                float f = v[r];
                Y1[(size_t)(row + r) * N2DIM + col] = f;
                s1[n] += f;
                s2[n] += f * f;
            }
        }
    }
#pragma unroll
    for (int n = 0; n < 2; ++n) {
        s1[n] += __shfl_xor(s1[n], 16, 64);
        s1[n] += __shfl_xor(s1[n], 32, 64);
        s2[n] += __shfl_xor(s2[n], 16, 64);
        s2[n] += __shfl_xor(s2[n], 32, 64);
    }
    if (l < 16) {
#pragma unroll
        for (int n = 0; n < 2; ++n) {
            const int col = wn * 32 + n * 16 + l;
            atomicAdd(&stats[col], s1[n]);
            atomicAdd(&stats[N2DIM + col], s2[n]);
        }
    }
}

// ---------------------------------------------------------------------------
// K6: out = relu(bn1(y1)), BN1 finalize inlined per block.
// ---------------------------------------------------------------------------
__global__ __launch_bounds__(256) void bn_out_kernel(
    const float* __restrict__ Y1, const float* __restrict__ stats1,
    const float* __restrict__ g1, const float* __restrict__ beta1,
    float* __restrict__ out)
{
    __shared__ float sgm[N2DIM], sga[N2DIM];
    const int tid = threadIdx.x;
    if (tid < N2DIM) {
        const float inv = 1.0f / (float)M_TOT;
        float mean = stats1[tid] * inv;
        float var  = stats1[N2DIM + tid] * inv - mean * mean;
        float m = g1[tid] * rsqrtf(var + 1e-5f);
        sgm[tid] = m;
        sga[tid] = beta1[tid] - mean * m;
    }
    __syncthreads();

    const int total = M_TOT * N2DIM / 4;
    for (int i = blockIdx.x * 256 + tid; i < total; i += gridDim.x * 256) {
        float4 v = ((const float4*)Y1)[i];
        const int cg = (i & 31) * 4;
        float4 m = *(const float4*)(sgm + cg);
        float4 a = *(const float4*)(sga + cg);
        float4 o;
        o.x = fmaxf(fmaf(v.x, m.x, a.x), 0.f);
        o.y = fmaxf(fmaf(v.y, m.y, a.y), 0.f);
        o.z = fmaxf(fmaf(v.z, m.z, a.z), 0.f);
        o.w = fmaxf(fmaf(v.w, m.w, a.w), 0.f);
        ((float4*)out)[i] = o;
    }
}

// ---------------------------------------------------------------------------
// launch
// ---------------------------------------------------------------------------
extern "C" void kernel_launch(void* const* d_in, const int* in_sizes, int n_in,
                              void* d_out, int out_size, void* d_ws, size_t ws_size,
                              hipStream_t stream)
{
    const float* uxyz  = (const float*)d_in[0];
    const float* kxyz  = (const float*)d_in[1];
    const float* upts  = (const float*)d_in[2];
    const float* kpts  = (const float*)d_in[3];
    const float* W0    = (const float*)d_in[4];
    const float* g0    = (const float*)d_in[6];
    const float* beta0 = (const float*)d_in[7];
    const float* W1    = (const float*)d_in[8];
    const float* g1    = (const float*)d_in[10];
    const float* beta1 = (const float*)d_in[11];
    float* out = (float*)d_out;

    char* ws = (char*)d_ws;
    const size_t off_x   = 0;                       // x bf16 [M][384]; y1 f32 aliased later
    const size_t off_y0  = 50331648;                // y0 bf16 [M][256]; cand+kpack aliased earlier
    const size_t off_w0  = off_y0 + 33554432;
    const size_t off_w1  = off_w0 + 196608;
    const size_t off_f   = off_w1 + 65536;

    unsigned short* x    = (unsigned short*)(ws + off_x);
    float*          y1   = (float*)(ws + off_x);
    unsigned short* y0   = (unsigned short*)(ws + off_y0);
    unsigned int*   cand = (unsigned int*)(ws + off_y0);          // 6.3 MB
    float4*         kpack = (float4*)(ws + off_y0 + 8388608);     // 256 KB
    unsigned short* wb0  = (unsigned short*)(ws + off_w0);
    unsigned short* wb1  = (unsigned short*)(ws + off_w1);
    float* F = (float*)(ws + off_f);
    float* stats0 = F;           // [512]
    float* stats1 = F + 512;     // [256]

    hipMemsetAsync(stats0, 0, 768 * sizeof(float), stream);

    cvt_w_kernel<<<384, 256, 0, stream>>>(W0, W1, kxyz, wb0, wb1, kpack);
    nn_cand_kernel<<<2048, 256, 0, stream>>>(uxyz, kpack, cand);
    merge_interp_kernel<<<1024, 256, 0, stream>>>(cand, kpack, uxyz, upts, kpts, x);
    gemm1_kernel<<<M_TOT / 128, 512, 0, stream>>>(x, wb0, y0, stats0);
    gemm2_kernel<<<M_TOT / 128, 512, 0, stream>>>(y0, wb1, stats0, g0, beta0, y1, stats1);
    bn_out_kernel<<<2048, 256, 0, stream>>>(y1, stats1, g1, beta1, out);
}